// Round 4
// baseline (331.139 us; speedup 1.0000x reference)
//
#include <hip/hip_runtime.h>

#define OUT_F 16384
#define IN_F  4096
#define BATCH 32
#define GS    128
#define NG    (IN_F / GS)   // 32 groups

// ---------------------------------------------------------------------------
// Kernel 1: transpose x[32][4096] -> xT[4096][32] so that x[:,k] is a
// contiguous 128B row (enables wave-uniform s_load broadcast in the GEMV).
// ---------------------------------------------------------------------------
__global__ void xT_kernel(const float* __restrict__ x, float* __restrict__ xT) {
    int gid = blockIdx.x * blockDim.x + threadIdx.x;  // 0..131071
    int k = gid >> 5;
    int b = gid & 31;
    // gid == k*32 + b  -> coalesced store
    xT[gid] = x[(size_t)b * IN_F + k];
}

// ---------------------------------------------------------------------------
// Kernel 2: main int4-dequant GEMV, weight-bandwidth bound.
// Grid: 256 blocks (one per 64-output tile), 512 threads = 8 waves.
// Wave w handles k in [w*512, w*512+512): 32 chunks of 16 k.
// Per chunk: coalesced global->reg prefetch, ds_write to private LDS tile
// [64 rows][20 words padded], then compute with lane = output row and
// wave-uniform k so x comes from SGPRs.
// ---------------------------------------------------------------------------
__global__ __launch_bounds__(512, 1) void int4linear_kernel(
    const int* __restrict__ w, const float* __restrict__ scales,
    const float* __restrict__ bias, const float* __restrict__ xT,
    float* __restrict__ out) {
    // 8 waves * 64 rows * 20 words * 4B = 40960 B (also reused for reduction)
    __shared__ int stage[8 * 64 * 20];

    const int tid  = threadIdx.x;
    const int wave = tid >> 6;
    const int lane = tid & 63;
    const int o_base  = blockIdx.x * 64;
    const int o       = o_base + lane;
    const int k_start = wave * 512;
    int* my = stage + wave * (64 * 20);

    float acc[32];
#pragma unroll
    for (int b = 0; b < 32; ++b) acc[b] = 0.f;

    // staging geometry: iter i covers rows i*16 + (lane>>2), 4 lanes/row * 16B
    const int srow  = lane >> 2;        // 0..15
    const int skoff = (lane & 3) * 4;   // 0,4,8,12 (k offset in ints)
    const int lds_base = srow * 20 + skoff;

    int4 ra[4], rb[4];
    // prefetch chunk 0
    {
        const int* g = w + (size_t)(o_base + srow) * IN_F + k_start + skoff;
#pragma unroll
        for (int i = 0; i < 4; ++i)
            ra[i] = *(const int4*)(g + (size_t)i * 16 * IN_F);
    }

    float sc = 0.f;
    for (int c = 0; c < 32; ++c) {
        const int k0 = k_start + c * 16;

        // prefetch next chunk into the other register set (overlaps compute)
        if (c < 31) {
            const int* g = w + (size_t)(o_base + srow) * IN_F + (k0 + 16) + skoff;
            if (c & 1) {
#pragma unroll
                for (int i = 0; i < 4; ++i)
                    ra[i] = *(const int4*)(g + (size_t)i * 16 * IN_F);
            } else {
#pragma unroll
                for (int i = 0; i < 4; ++i)
                    rb[i] = *(const int4*)(g + (size_t)i * 16 * IN_F);
            }
        }

        // write current chunk to this wave's private LDS tile
        if (c & 1) {
#pragma unroll
            for (int i = 0; i < 4; ++i)
                *(int4*)(my + lds_base + i * 16 * 20) = rb[i];
        } else {
#pragma unroll
            for (int i = 0; i < 4; ++i)
                *(int4*)(my + lds_base + i * 16 * 20) = ra[i];
        }

        // per-group scale for this lane's output row (changes every 8 chunks)
        if ((c & 7) == 0) {
            int g = (k_start + c * 16) / GS;
            sc = scales[(size_t)o * NG + g];
        }

        // compute: lane = output row, k is wave-uniform -> x via s_load
#pragma unroll
        for (int kk = 0; kk < 16; kk += 4) {
            int4 q = *(const int4*)(my + lane * 20 + kk);
#pragma unroll
            for (int j = 0; j < 4; ++j) {
                int qv = (j == 0) ? q.x : (j == 1) ? q.y : (j == 2) ? q.z : q.w;
                float wf = (float)qv * sc;
                const float* xr = xT + (size_t)(k0 + kk + j) * BATCH;
#pragma unroll
                for (int b = 0; b < 32; ++b)
                    acc[b] = fmaf(wf, xr[b], acc[b]);
            }
        }
    }

    // -------- cross-wave reduction (8 partials -> 1) --------
    __syncthreads();
    float* red = (float*)stage;  // [4][32][64] f32 = 32768 B <= 40960 B
    if (wave >= 4) {
#pragma unroll
        for (int b = 0; b < 32; ++b)
            red[((wave - 4) * 32 + b) * 64 + lane] = acc[b];
    }
    __syncthreads();
    if (wave < 4) {
#pragma unroll
        for (int b = 0; b < 32; ++b) {
            acc[b] += red[(wave * 32 + b) * 64 + lane];
            red[(wave * 32 + b) * 64 + lane] = acc[b];
        }
    }
    __syncthreads();
#pragma unroll
    for (int i = 0; i < 4; ++i) {
        int p  = i * 512 + tid;     // 0..2047
        int oo = p & 63;
        int b  = p >> 6;
        float s = red[(0 * 32 + b) * 64 + oo] + red[(1 * 32 + b) * 64 + oo] +
                  red[(2 * 32 + b) * 64 + oo] + red[(3 * 32 + b) * 64 + oo];
        out[(size_t)b * OUT_F + o_base + oo] = s + bias[o_base + oo];
    }
}

extern "C" void kernel_launch(void* const* d_in, const int* in_sizes, int n_in,
                              void* d_out, int out_size, void* d_ws, size_t ws_size,
                              hipStream_t stream) {
    const float* x      = (const float*)d_in[0];
    const int*   w      = (const int*)d_in[1];
    const float* scales = (const float*)d_in[2];
    const float* bias   = (const float*)d_in[3];
    float*       out    = (float*)d_out;
    float*       xT     = (float*)d_ws;  // 4096*32*4 = 512 KB scratch

    hipLaunchKernelGGL(xT_kernel, dim3((BATCH * IN_F) / 256), dim3(256), 0, stream,
                       x, xT);
    hipLaunchKernelGGL(int4linear_kernel, dim3(OUT_F / 64), dim3(512), 0, stream,
                       w, scales, bias, xT, out);
}

// Round 5
// 80.742 us; speedup vs baseline: 4.1012x; 4.1012x over previous
//
#include <hip/hip_runtime.h>

#define OUT_F 16384
#define IN_F  4096
#define BATCH 32
#define GS    128
#define NG    (IN_F / GS)   // 32

typedef __attribute__((ext_vector_type(4)))  int    int4v;
typedef __attribute__((ext_vector_type(8)))  short  short8v;
typedef __attribute__((ext_vector_type(16))) float  floatx16;

// f32 -> bf16 round-to-nearest-even, bit-level (no __hip_bfloat16 ABI dependence)
static __device__ __forceinline__ short f32_bf16_rne(float f) {
    unsigned u = __float_as_uint(f);
    u += 0x7FFFu + ((u >> 16) & 1u);
    return (short)(u >> 16);
}

// ---------------------------------------------------------------------------
// Pre-kernel: build x B-fragments in MFMA layout, bf16.
// For 32x32x16_bf16, B-frag of k-chunk c: lane l holds x[b = l&31][k = c*16 +
// (l>>5)*8 + i], i=0..7. Stored flat: xf[((c*64 + l)*8 + i)]  (256 KB).
// ---------------------------------------------------------------------------
__global__ void xfrag_kernel(const float* __restrict__ x, short* __restrict__ xf) {
    int gid = blockIdx.x * blockDim.x + threadIdx.x;  // 0..131071
    int i = gid & 7;
    int l = (gid >> 3) & 63;
    int c = gid >> 9;
    int b = l & 31;
    int k = c * 16 + (l >> 5) * 8 + i;
    xf[gid] = f32_bf16_rne(x[(size_t)b * IN_F + k]);
}

// ---------------------------------------------------------------------------
// Main kernel: 512 blocks x 512 threads (8 waves). Block owns 32 output rows;
// wave wv covers k in [wv*512, wv*512+512) as 32 chunks of K=16.
// Per chunk/lane: 2x dwordx4 weight ints (fragment layout, one lane per
// weight), dequant to bf16, 1 coalesced B-frag load, 1 MFMA. No main-loop LDS.
// ---------------------------------------------------------------------------
__global__ __launch_bounds__(512) void int4linear_mfma(
    const int* __restrict__ w, const float* __restrict__ scales,
    const float* __restrict__ bias, const short* __restrict__ xf,
    float* __restrict__ out)
{
    __shared__ float red[8 * 16 * 64];  // 32 KB, epilogue only

    const int tid = threadIdx.x;
    const int wv  = tid >> 6;
    const int l   = tid & 63;
    const int row = l & 31;          // A-fragment row (o_local)
    const int kh  = l >> 5;          // k-half within chunk
    const int o_base = blockIdx.x * 32;
    const int o = o_base + row;
    const int k_start = wv * 512;

    floatx16 acc = {};

    // lane's weight pointer for chunk 0: 8 consecutive ints at its k-window
    const int* p = w + (size_t)o * IN_F + k_start + kh * 8;

    int4v a0, b0, a1, b1;
    a0 = *(const int4v*)p;
    b0 = *(const int4v*)(p + 4);

    float sc = 0.f;
#pragma unroll
    for (int c = 0; c < 32; ++c) {
        // 1-deep prefetch of next chunk's weights (static select under unroll)
        if (c + 1 < 32) {
            const int* pn = p + (c + 1) * 16;
            if (c & 1) { a0 = *(const int4v*)pn; b0 = *(const int4v*)(pn + 4); }
            else       { a1 = *(const int4v*)pn; b1 = *(const int4v*)(pn + 4); }
        }
        // per-group scale for this lane's row (chunk k-window stays in-group)
        if ((c & 7) == 0) sc = scales[(size_t)o * NG + wv * 4 + (c >> 3)];

        int4v qa = (c & 1) ? a1 : a0;
        int4v qb = (c & 1) ? b1 : b0;

        // B fragment: coalesced 16 B/lane from precomputed layout (L2/L3-hot)
        short8v bf = *(const short8v*)(xf + (size_t)((wv * 32 + c) * 64 + l) * 8);

        // dequant 8 weights -> bf16 A fragment (each weight handled once)
        short8v af;
        af[0] = f32_bf16_rne((float)qa[0] * sc);
        af[1] = f32_bf16_rne((float)qa[1] * sc);
        af[2] = f32_bf16_rne((float)qa[2] * sc);
        af[3] = f32_bf16_rne((float)qa[3] * sc);
        af[4] = f32_bf16_rne((float)qb[0] * sc);
        af[5] = f32_bf16_rne((float)qb[1] * sc);
        af[6] = f32_bf16_rne((float)qb[2] * sc);
        af[7] = f32_bf16_rne((float)qb[3] * sc);

        acc = __builtin_amdgcn_mfma_f32_32x32x16_bf16(af, bf, acc, 0, 0, 0);
    }

    // -------- epilogue: 8-way cross-wave reduce + bias + coalesced store ----
#pragma unroll
    for (int r = 0; r < 16; ++r)
        red[(wv * 16 + r) * 64 + l] = acc[r];
    __syncthreads();

    // C/D layout (verified): col(b) = lane&31, row(o) = (reg&3)+8*(reg>>2)+4*(lane>>5)
    // Inverse: reg = (ol&3)+4*(ol>>3), lane = b + 32*((ol>>2)&1)
#pragma unroll
    for (int t2 = 0; t2 < 2; ++t2) {
        int t  = t2 * 512 + tid;    // 0..1023 output elems of this block
        int b  = t >> 5;            // batch 0..31
        int ol = t & 31;            // o_local 0..31 (consecutive -> coalesced)
        int rr = (ol & 3) + 4 * (ol >> 3);
        int ll = b + 32 * ((ol >> 2) & 1);
        float s = 0.f;
#pragma unroll
        for (int wvi = 0; wvi < 8; ++wvi)
            s += red[(wvi * 16 + rr) * 64 + ll];
        out[(size_t)b * OUT_F + o_base + ol] = s + bias[o_base + ol];
    }
}

extern "C" void kernel_launch(void* const* d_in, const int* in_sizes, int n_in,
                              void* d_out, int out_size, void* d_ws, size_t ws_size,
                              hipStream_t stream) {
    const float* x      = (const float*)d_in[0];
    const int*   w      = (const int*)d_in[1];
    const float* scales = (const float*)d_in[2];
    const float* bias   = (const float*)d_in[3];
    float*       out    = (float*)d_out;
    short*       xfrag  = (short*)d_ws;  // 256 KB fragment buffer

    hipLaunchKernelGGL(xfrag_kernel, dim3(512), dim3(256), 0, stream, x, xfrag);
    hipLaunchKernelGGL(int4linear_mfma, dim3(OUT_F / 32), dim3(512), 0, stream,
                       w, scales, bias, xfrag, out);
}

// Round 6
// 63.495 us; speedup vs baseline: 5.2152x; 1.2716x over previous
//
#include <hip/hip_runtime.h>

#define OUT_F 16384
#define IN_F  4096
#define BATCH 32
#define GS    128
#define NG    32           // IN_F / GS
#define KT    256          // ints per row per K-tile
#define NT    16           // IN_F / KT

typedef __attribute__((ext_vector_type(4)))  int    int4v;
typedef __attribute__((ext_vector_type(8)))  short  short8v;
typedef __attribute__((ext_vector_type(16))) float  floatx16;

// f32 -> bf16 round-to-nearest-even (bit-level)
static __device__ __forceinline__ short f32_bf16_rne(float f) {
    unsigned u = __float_as_uint(f);
    u += 0x7FFFu + ((u >> 16) & 1u);
    return (short)(u >> 16);
}

// ---------------------------------------------------------------------------
// Pre-kernel: x B-fragments in MFMA layout (verified in round 5).
// Lane l of chunk c holds x[b = l&31][k = c*16 + (l>>5)*8 + i], i=0..7.
// ---------------------------------------------------------------------------
__global__ void xfrag_kernel(const float* __restrict__ x, short* __restrict__ xf) {
    int gid = blockIdx.x * blockDim.x + threadIdx.x;  // 0..131071
    int i = gid & 7;
    int l = (gid >> 3) & 63;
    int c = gid >> 9;
    int b = l & 31;
    int k = c * 16 + (l >> 5) * 8 + i;
    xf[gid] = f32_bf16_rne(x[(size_t)b * IN_F + k]);
}

// ---------------------------------------------------------------------------
// Main kernel: 512 blocks x 512 threads (8 waves), 32 output rows per block.
// Per K-tile [32 rows][256 ints]: coalesced staging (1 KB contiguous per
// wave-load, 4 loads/thread), XOR-swizzled LDS, double-buffered, one barrier
// per tile. Wave wv computes chunks {2wv, 2wv+1} (K=16 each) via
// mfma_f32_32x32x16_bf16; 8-way cross-wave reduce at the end.
// ---------------------------------------------------------------------------
__global__ __launch_bounds__(512) void int4linear_mfma(
    const int* __restrict__ w, const float* __restrict__ scales,
    const float* __restrict__ bias, const short* __restrict__ xf,
    float* __restrict__ out)
{
    __shared__ int lds[2 * 32 * KT];   // 64 KB double buffer (also epilogue red)

    const int tid = threadIdx.x;
    const int wv  = tid >> 6;
    const int l   = tid & 63;
    const int row = l & 31;          // A-fragment row (o_local)
    const int kh  = l >> 5;          // k-half within chunk
    const int rm  = row & 15;        // swizzle mask
    const int o_base = blockIdx.x * 32;
    const int o   = o_base + row;

    floatx16 acc = {};
    int4v pf[4];

    // ---- prologue: stage tile 0 ----
#pragma unroll
    for (int j = 0; j < 4; ++j) {
        int r = wv + 8 * j;
        pf[j] = *(const int4v*)(w + (size_t)(o_base + r) * IN_F + l * 4);
    }
#pragma unroll
    for (int j = 0; j < 4; ++j) {
        int r = wv + 8 * j;
        *(int4v*)(lds + r * KT + ((l ^ (r & 15)) << 2)) = pf[j];
    }
    __syncthreads();

    for (int t = 0; t < NT; ++t) {
        const int cur = (t & 1) * (32 * KT);
        const int nxt = ((t + 1) & 1) * (32 * KT);

        // issue next tile's global loads early (latency hides under compute)
        if (t + 1 < NT) {
#pragma unroll
            for (int j = 0; j < 4; ++j) {
                int r = wv + 8 * j;
                pf[j] = *(const int4v*)(w + (size_t)(o_base + r) * IN_F
                                          + (t + 1) * KT + l * 4);
            }
        }

        // per-group scale: tile t spans groups {2t, 2t+1}; wave's chunks stay
        // in group 2t + (wv>=4)
        const float sc = scales[(size_t)o * NG + 2 * t + (wv >> 2)];

#pragma unroll
        for (int c2 = 0; c2 < 2; ++c2) {
            const int ch = 2 * wv + c2;           // chunk 0..15 within tile
            const int u0 = ch * 4 + kh * 2;       // 16B-unit index
            const int4v qa = *(const int4v*)(lds + cur + row * KT + ((u0 ^ rm) << 2));
            const int4v qb = *(const int4v*)(lds + cur + row * KT + (((u0 + 1) ^ rm) << 2));
            const short8v bf = *(const short8v*)(xf + ((size_t)((t * 16 + ch) * 64 + l)) * 8);

            short8v af;
            af[0] = f32_bf16_rne((float)qa[0] * sc);
            af[1] = f32_bf16_rne((float)qa[1] * sc);
            af[2] = f32_bf16_rne((float)qa[2] * sc);
            af[3] = f32_bf16_rne((float)qa[3] * sc);
            af[4] = f32_bf16_rne((float)qb[0] * sc);
            af[5] = f32_bf16_rne((float)qb[1] * sc);
            af[6] = f32_bf16_rne((float)qb[2] * sc);
            af[7] = f32_bf16_rne((float)qb[3] * sc);

            acc = __builtin_amdgcn_mfma_f32_32x32x16_bf16(af, bf, acc, 0, 0, 0);
        }

        // write next tile to the other buffer (compiler waits vmcnt on pf)
        if (t + 1 < NT) {
#pragma unroll
            for (int j = 0; j < 4; ++j) {
                int r = wv + 8 * j;
                *(int4v*)(lds + nxt + r * KT + ((l ^ (r & 15)) << 2)) = pf[j];
            }
        }
        __syncthreads();
    }

    // ---- epilogue: 8-way cross-wave reduce + bias (verified layout) ----
    float* red = (float*)lds;  // 32 KB <= 64 KB
#pragma unroll
    for (int r = 0; r < 16; ++r)
        red[(wv * 16 + r) * 64 + l] = acc[r];
    __syncthreads();

    // C/D layout: col(b) = lane&31, row(o) = (reg&3)+8*(reg>>2)+4*(lane>>5)
#pragma unroll
    for (int t2 = 0; t2 < 2; ++t2) {
        int tt = t2 * 512 + tid;    // 0..1023 output elems of this block
        int b  = tt >> 5;           // batch 0..31
        int ol = tt & 31;           // o_local (consecutive -> coalesced)
        int rr = (ol & 3) + 4 * (ol >> 3);
        int ll = b + 32 * ((ol >> 2) & 1);
        float s = 0.f;
#pragma unroll
        for (int wvi = 0; wvi < 8; ++wvi)
            s += red[(wvi * 16 + rr) * 64 + ll];
        out[(size_t)b * OUT_F + o_base + ol] = s + bias[o_base + ol];
    }
}

extern "C" void kernel_launch(void* const* d_in, const int* in_sizes, int n_in,
                              void* d_out, int out_size, void* d_ws, size_t ws_size,
                              hipStream_t stream) {
    const float* x      = (const float*)d_in[0];
    const int*   w      = (const int*)d_in[1];
    const float* scales = (const float*)d_in[2];
    const float* bias   = (const float*)d_in[3];
    float*       out    = (float*)d_out;
    short*       xfrag  = (short*)d_ws;  // 256 KB fragment buffer

    hipLaunchKernelGGL(xfrag_kernel, dim3(512), dim3(256), 0, stream, x, xfrag);
    hipLaunchKernelGGL(int4linear_mfma, dim3(OUT_F / 32), dim3(512), 0, stream,
                       w, scales, bias, xfrag, out);
}